// Round 3
// baseline (350.800 us; speedup 1.0000x reference)
//
#include <hip/hip_runtime.h>
#include <cmath>

// B=64, L=512, H=64, 2H=128, OUT=5
static constexpr int kB = 64, kL = 512, kH = 64, kH2 = 128, kOut = 5;

typedef short bf16x8 __attribute__((ext_vector_type(8)));
typedef float f32x4  __attribute__((ext_vector_type(4)));
typedef float f32x16 __attribute__((ext_vector_type(16)));

__device__ __forceinline__ unsigned short f2bf(float f) {
  unsigned u = __float_as_uint(f);
  unsigned r = (u + 0x7FFFu + ((u >> 16) & 1u)) >> 16;   // RNE
  return (unsigned short)r;
}

__device__ __forceinline__ void cvt8(const f32x4& v0, const f32x4& v1,
                                     bf16x8& hi, bf16x8& lo) {
  #pragma unroll
  for (int j = 0; j < 4; ++j) {
    unsigned short h0 = f2bf(v0[j]);
    unsigned short h1 = f2bf(v1[j]);
    hi[j]     = (short)h0;
    hi[j + 4] = (short)h1;
    lo[j]     = (short)f2bf(v0[j] - __uint_as_float(((unsigned)h0) << 16));
    lo[j + 4] = (short)f2bf(v1[j] - __uint_as_float(((unsigned)h1) << 16));
  }
}

// ---- prepass: V fp32 -> bf16 row-major [i][p][q]; W -> Wt bf16 [i][p] ----
__global__ void prep_k(const float* __restrict__ V, const float* __restrict__ W,
                       unsigned short* __restrict__ vhi, unsigned short* __restrict__ wt) {
  int idx = blockIdx.x * 256 + threadIdx.x;
  if (idx < kH * kH2 * kH2) {
    vhi[idx] = f2bf(V[idx]);
  } else {
    int widx = idx - kH * kH2 * kH2;
    if (widx < kH * kH2) {
      int i = widx >> 7, p = widx & 127;
      wt[widx] = f2bf(W[p * kH + i]);      // Wt[i][p] = W[p][i]
    }
  }
}

// ---- fused combine level, 32x32x16 MFMA edition ----
// D[p,m] = sum_q V_i[p,q]*C[m,q]  (A=V rows, B=C rows as K-slices, hi+lo chained)
// R[m,i] = sum_p C32[m,p]*D[p,m]  via in-lane dot over 16 C/D regs + shfl_xor(32)
// Wx via one 32x32 MFMA tile per wave, held in registers with bias folded in.
// V_i double-buffered in LDS (2x32KB), staged with global_load_lds width=16,
// XOR-16 chunk swizzle: phys_chunk(p,c16) = p*16 + (c16 ^ (p&15)).
template<bool FIRST>
__global__ __launch_bounds__(256, 2) void combine3_k(
    const float* __restrict__ in, const int* __restrict__ tokens,
    const float* __restrict__ embed, const unsigned short* __restrict__ vhi,
    const unsigned short* __restrict__ wt, const float* __restrict__ bias,
    float* __restrict__ out, int M, int IS)
{
  __shared__ unsigned short Vs[2][kH2 * kH2];   // 2 x 32 KB

  const int t    = threadIdx.x;
  const int lane = t & 63, w = t >> 6;
  const int hl   = lane >> 5;                   // K-half selector
  const int r31  = lane & 31;
  const int m0   = (int)blockIdx.x * 128;
  const int i0   = (int)blockIdx.y * IS;
  const int Mrows = (M < 128) ? M : 128;
  const bool has_rows = (w * 32) < Mrows;

  auto stageV = [&](int buf, int i) {
    const unsigned short* vsrc = vhi + (size_t)i * (kH2 * kH2);
    char* base = (char*)&Vs[buf][0];
    #pragma unroll
    for (int r = 0; r < 8; ++r) {
      int chunk = w * 512 + r * 64 + lane;      // physical 16B chunk 0..2047
      int p  = chunk >> 4;
      int c16 = (chunk & 15) ^ (p & 15);        // logical k-chunk
      const unsigned short* g = vsrc + p * kH2 + c16 * 8;
      __builtin_amdgcn_global_load_lds(
          (const __attribute__((address_space(1))) unsigned int*)g,
          (__attribute__((address_space(3))) unsigned int*)(base + (size_t)chunk * 16),
          16, 0, 0);
    }
  };

  stageV(0, i0);                                // overlaps with setup below

  bf16x8 bh[8], bl[8];                          // C as B-frags, K=128 in 8 slices
  f32x4  Cred[4][4];                            // C fp32, dot-layout per lane
  float  wxr[8];                                // Wx + bias for this lane's 8 i-rows

  if (has_rows) {
    const int m = m0 + w * 32 + r31;
    const float* crow = nullptr;
    int tokA = 0, tokB = 0;
    if (FIRST) {
      int b = m >> 8, j = m & 255;              // Nout=256 at level 1
      tokA = tokens[b * kL + 2 * j];
      tokB = tokens[b * kL + 2 * j + 1];
    } else {
      crow = in + (size_t)m * kH2;
    }
    #pragma unroll
    for (int ks = 0; ks < 8; ++ks) {            // B-frag slice: k = ks*16 + hl*8 ..+8
      int q0 = ks * 16 + hl * 8;
      const float* src = FIRST
          ? (embed + (size_t)(q0 < 64 ? tokA : tokB) * kH + (q0 & 63))
          : (crow + q0);
      f32x4 v0 = *(const f32x4*)src;
      f32x4 v1 = *(const f32x4*)(src + 4);
      cvt8(v0, v1, bh[ks], bl[ks]);
    }
    #pragma unroll
    for (int pt = 0; pt < 4; ++pt)
      #pragma unroll
      for (int j = 0; j < 4; ++j) {             // Cred: p = pt*32 + 4*hl + j*8 ..+4
        int p0 = pt * 32 + hl * 4 + j * 8;
        const float* src = FIRST
            ? (embed + (size_t)(p0 < 64 ? tokA : tokB) * kH + (p0 & 63))
            : (crow + p0);
        Cred[pt][j] = *(const f32x4*)src;
      }
    // Wx: D'[i,m] = sum_p Wt[i,p] C[m,p], one 32x32 tile (rows i0..i0+31, clamped)
    {
      int irow = i0 + r31; if (irow > kH - 1) irow = kH - 1;
      f32x16 acc = {};
      #pragma unroll
      for (int ks = 0; ks < 8; ++ks) {
        bf16x8 a = *(const bf16x8*)(wt + (size_t)irow * kH2 + ks * 16 + hl * 8);
        acc = __builtin_amdgcn_mfma_f32_32x32x16_bf16(a, bh[ks], acc, 0, 0, 0);
      }
      #pragma unroll
      for (int reg = 0; reg < 8; ++reg) {
        int ii = (reg & 3) + 8 * (reg >> 2) + 4 * hl;   // 0..15
        wxr[reg] = acc[reg] + bias[i0 + ii];
      }
    }
  }

  __syncthreads();                              // buf0 ready (vmcnt drained)

  for (int ic = 0; ic < IS; ++ic) {
    const int buf = ic & 1;
    if (ic + 1 < IS) stageV(buf ^ 1, i0 + ic + 1);   // async, lands during compute

    if (has_rows) {
      float gsum = 0.f;
      const char* vbase = (const char*)&Vs[buf][0];
      #pragma unroll
      for (int pt = 0; pt < 4; ++pt) {
        const int p  = pt * 32 + r31;           // A-frag row = V row p
        const int pm = p & 15;
        const char* vrow = vbase + (size_t)p * 256;
        f32x16 acc = {};
        #pragma unroll
        for (int ks = 0; ks < 8; ++ks) {
          int cc = (ks * 2 + hl) ^ pm;          // swizzled chunk
          bf16x8 vf = *(const bf16x8*)(vrow + cc * 16);
          acc = __builtin_amdgcn_mfma_f32_32x32x16_bf16(vf, bh[ks], acc, 0, 0, 0);
          acc = __builtin_amdgcn_mfma_f32_32x32x16_bf16(vf, bl[ks], acc, 0, 0, 0);
        }
        #pragma unroll
        for (int reg = 0; reg < 16; ++reg)      // p' = pt*32+(reg&3)+8*(reg>>2)+4*hl
          gsum = fmaf(Cred[pt][reg >> 2][reg & 3], acc[reg], gsum);
      }
      gsum += __shfl_xor(gsum, 32);             // join the two p-halves
      if (hl == ((ic >> 2) & 1)) {              // lane holding wx for i=ic
        int reg = (ic & 3) + 4 * (ic >> 3);
        out[(size_t)(m0 + w * 32 + r31) * kH + i0 + ic] = tanhf(gsum + wxr[reg]);
      }
    }
    __syncthreads();                            // drains stage(ic+1); buf reads done
  }
}

// ---- head: logits = root @ Wout + bout; log_softmax ----
__global__ void head_k(const float* __restrict__ root,
                       const float* __restrict__ Wout,
                       const float* __restrict__ bout,
                       float* __restrict__ out) {
  int b = threadIdx.x;
  float l[kOut];
  #pragma unroll
  for (int o = 0; o < kOut; ++o) l[o] = bout[o];
  for (int h = 0; h < kH; ++h) {
    float r = root[b * kH + h];
    #pragma unroll
    for (int o = 0; o < kOut; ++o) l[o] = fmaf(r, Wout[h * kOut + o], l[o]);
  }
  float mx = l[0];
  #pragma unroll
  for (int o = 1; o < kOut; ++o) mx = fmaxf(mx, l[o]);
  float s = 0.f;
  #pragma unroll
  for (int o = 0; o < kOut; ++o) s += expf(l[o] - mx);
  float lse = logf(s);
  #pragma unroll
  for (int o = 0; o < kOut; ++o) out[b * kOut + o] = l[o] - mx - lse;
}

extern "C" void kernel_launch(void* const* d_in, const int* in_sizes, int n_in,
                              void* d_out, int out_size, void* d_ws, size_t ws_size,
                              hipStream_t stream) {
  const int*   tokens = (const int*)  d_in[0];
  const float* embed  = (const float*)d_in[1];
  const float* V      = (const float*)d_in[2];
  const float* W      = (const float*)d_in[3];
  const float* bias   = (const float*)d_in[4];
  const float* Wout   = (const float*)d_in[5];
  const float* bout   = (const float*)d_in[6];
  float* out = (float*)d_out;

  // ws: vhi 2MB | wt 16KB | bufA 4MB | bufB 2MB
  char* ws = (char*)d_ws;
  unsigned short* vhi = (unsigned short*)ws;
  unsigned short* wt  = (unsigned short*)(ws + 2097152);
  float* bufA = (float*)(ws + 2097152 + 16384);
  float* bufB = (float*)(ws + 2097152 + 16384 + 4194304);

  int nprep = kH * kH2 * kH2 + kH * kH2;
  prep_k<<<dim3((nprep + 255) / 256), 256, 0, stream>>>(V, W, vhi, wt);

  const float* cur = nullptr;
  float* nxt = bufA;
  bool first = true;
  for (int Nout = 256; Nout >= 1; Nout >>= 1) {
    int M = kB * Nout;
    int gx = (M + 127) / 128;
    int IS = gx / 8; if (IS < 1) IS = 1; if (IS > 16) IS = 16;
    dim3 grid(gx, 64 / IS);
    if (first)
      combine3_k<true ><<<grid, 256, 0, stream>>>(nullptr, tokens, embed, vhi, wt, bias, nxt, M, IS);
    else
      combine3_k<false><<<grid, 256, 0, stream>>>(cur, nullptr, nullptr, vhi, wt, bias, nxt, M, IS);
    first = false;
    cur = nxt;
    nxt = (nxt == bufA) ? bufB : bufA;
  }
  head_k<<<1, 64, 0, stream>>>(cur, Wout, bout, out);   // cur == bufA after 9 levels
}